// Round 15
// baseline (606.903 us; speedup 1.0000x reference)
//
#include <hip/hip_runtime.h>
#include <hip/hip_bf16.h>
#include <stdint.h>

typedef __bf16 bf16_t;
typedef __attribute__((ext_vector_type(8))) __bf16 bf16x8;
typedef __attribute__((ext_vector_type(4))) __bf16 bf16x4;
typedef __attribute__((ext_vector_type(4))) float f32x4;

constexpr int IN_F   = 4096;
constexpr int OUT_F  = 4096;
constexpr int RANKC  = 12;
constexpr float SCAL = 16.0f / 12.0f;
constexpr int MTOT   = 4 * 4096;   // B*S = 16384
constexpr int NT     = IN_F / 64;  // 64 K-tiles

// prep kernel grid split (one-shot blocks: verified best; grid-stride regressed)
constexpr int CVT_BLOCKS  = (MTOT * IN_F) / (256 * 8);     // 32768
constexpr int FOLD_BLOCKS = (OUT_F * IN_F) / (256 * 4);    // 16384

typedef __attribute__((address_space(1))) const unsigned int uint_g;
typedef __attribute__((address_space(3))) unsigned int uint_l;

__device__ __forceinline__ void gload_lds16(const void* g, void* l) {
    __builtin_amdgcn_global_load_lds((uint_g*)(uintptr_t)g,
                                     (uint_l*)(uintptr_t)l,
                                     16, 0, 0);
}

// ---------------------------------------------------------------------------
// Kernel 1 (merged prep):
//   blocks [0, CVT_BLOCKS):      x fp32 -> bf16 (8 elems/thread)
//   blocks [CVT_BLOCKS, +FOLD):  Wb = bf16(W + SCAL * (P*sigma) Q^T)  (4/thr)
// ---------------------------------------------------------------------------
__global__ __launch_bounds__(256) void prep_kernel(
    const float* __restrict__ X,  bf16_t* __restrict__ Xb,
    const float* __restrict__ W,  const float* __restrict__ P,
    const float* __restrict__ sg, const float* __restrict__ Q,
    bf16_t* __restrict__ Wb)
{
    if (blockIdx.x < CVT_BLOCKS) {
        const size_t base = ((size_t)blockIdx.x * 256 + threadIdx.x) * 8;
        const float4 a = *reinterpret_cast<const float4*>(X + base);
        const float4 b = *reinterpret_cast<const float4*>(X + base + 4);
        bf16x8 ob;
        ob[0] = (bf16_t)a.x; ob[1] = (bf16_t)a.y; ob[2] = (bf16_t)a.z; ob[3] = (bf16_t)a.w;
        ob[4] = (bf16_t)b.x; ob[5] = (bf16_t)b.y; ob[6] = (bf16_t)b.z; ob[7] = (bf16_t)b.w;
        *reinterpret_cast<bf16x8*>(Xb + base) = ob;
    } else {
        const int t    = (blockIdx.x - CVT_BLOCKS) * 256 + threadIdx.x;
        const int base = t * 4;
        const int o    = base >> 12;            // IN_F = 4096 = 2^12
        const int i0   = base & (IN_F - 1);

        float psig[RANKC];
#pragma unroll
        for (int r = 0; r < RANKC; ++r)
            psig[r] = P[o * RANKC + r] * sg[r] * SCAL;

        const float4 w = *reinterpret_cast<const float4*>(W + base);
        float out[4] = {w.x, w.y, w.z, w.w};
#pragma unroll
        for (int j = 0; j < 4; ++j) {
            const float* q = Q + (size_t)(i0 + j) * RANKC;
            float d = 0.0f;
#pragma unroll
            for (int r = 0; r < RANKC; ++r) d += psig[r] * q[r];
            out[j] += d;
        }
        bf16x4 ob;
#pragma unroll
        for (int j = 0; j < 4; ++j) ob[j] = (bf16_t)out[j];
        *reinterpret_cast<bf16x4*>(Wb + base) = ob;
    }
}

// ---------------------------------------------------------------------------
// Kernel 2: 256x256 4-phase GEMM, ONE barrier + ONE vmcnt per K-tile.
// Full-LDS (160 KB): A TRIPLE-buffered (a0,a1,a2; staged 2 tiles ahead),
// B double-buffered (b0,b1; staged 1 tile ahead).
//
// Stage map: p1(t): B(t+1)x4 -> Bbuf[(t+1)&1];  p2(t): A(t+2)x4 ->
// Abuf[(t+2)%3];  p3/p4: none.
// Single sync point at p3(t)-end: VMW(4)+LGKM0+BAR.
//   FIFO queue: after wait 4 [A(t+2)]; p1 +4 = 8; p2 +4 = 12; VMW(4) keeps
//   the 4 newest (A(t+2)), drains A(t+1)+B(t+1). Never 0.
// Publish: A(t) staged p2(t-2), B(t) staged p1(t-1) -- both drained at
//   p3(t-1)-end, one barrier before ANY read of them (phase-head reads at
//   p4(t-1)/p1(t)/p2(t)/p3(t)). All-waves guarantee; R4 race class excluded.
// WAR: LGKM0 before the barrier forces every phase-head ds_read (issued
//   >=1 phase earlier, hidden under MFMA) complete before ANY wave passes;
//   window writes target Bbuf[(t+2)&1]=Bbuf[t&1] / Abuf[(t+3)%3]=Abuf[t%3],
//   disjoint from all window reads (A(t+1),B(t+1)) -- checked per region.
// Tail: clamped stages write junk duplicates into buffers whose next read
//   is either real re-staged data or dead registers; counts preserved.
// 1 block/CU (160 KB LDS; also register-mandatory per R10).
// ---------------------------------------------------------------------------
__device__ __forceinline__ void stage64(const bf16_t* __restrict__ g, size_t grow0,
                                        bf16_t* lt, int ldrow0, int kt, int tid)
{
    const int rr  = tid >> 3;                       // 0..63 within region
    const int c16 = (tid & 7) ^ (rr & 7);           // inverse-swizzled source chunk
    const bf16_t* src = g + (grow0 + (size_t)(ldrow0 + rr)) * IN_F + kt * 64 + c16 * 8;
    gload_lds16(src, lt + ldrow0 * 64 + tid * 8);   // linear LDS dest
}

#define VMW(N) asm volatile("s_waitcnt vmcnt(" #N ")" ::: "memory")
#define LGKM0  asm volatile("s_waitcnt lgkmcnt(0)" ::: "memory")
#define BAR    __builtin_amdgcn_s_barrier()
#define SB     __builtin_amdgcn_sched_barrier(0)

#define RD_A(DST, BUF, MH, KK) do {                                             \
    _Pragma("unroll")                                                           \
    for (int m_ = 0; m_ < 4; ++m_)                                              \
        DST[m_] = *(const bf16x8*)&BUF[(wm * 128 + (MH) * 64 + m_ * 16 + lr) * 64 \
                                       + (((KK) * 4 + hi) ^ (lr & 7)) * 8];     \
} while (0)

#define RD_B(BUF, KK) do {                                                      \
    _Pragma("unroll")                                                           \
    for (int n_ = 0; n_ < 4; ++n_)                                              \
        bq[KK][n_] = *(const bf16x8*)&BUF[(wn * 64 + n_ * 16 + lr) * 64         \
                                       + (((KK) * 4 + hi) ^ (lr & 7)) * 8];     \
} while (0)

#define MM(AF, KK, MH) do {                                                     \
    __builtin_amdgcn_s_setprio(1);                                              \
    _Pragma("unroll")                                                           \
    for (int m_ = 0; m_ < 4; ++m_)                                              \
        _Pragma("unroll")                                                       \
        for (int n_ = 0; n_ < 4; ++n_)                                          \
            acc[(MH) * 4 + m_][n_] = __builtin_amdgcn_mfma_f32_16x16x32_bf16(   \
                AF[m_], bq[KK][n_], acc[(MH) * 4 + m_][n_], 0, 0, 0);           \
    __builtin_amdgcn_s_setprio(0);                                              \
} while (0)

// CA_=Abuf[T%3], NA_=Abuf[(T+1)%3], SA_=Abuf[(T+2)%3],
// CB_=Bbuf[T&1],  NB_=Bbuf[(T+1)&1]
#define TILE(T, CA_, NA_, SA_, CB_, NB_) do {                                   \
    const int t1_ = ((T) + 1 < NT) ? (T) + 1 : NT - 1;                          \
    const int t2_ = ((T) + 2 < NT) ? (T) + 2 : NT - 1;                          \
    /* p1: consume (afA,bq0); prefetch (afB,bq1); stage B(t+1) full */          \
    stage64(Bm, bcol, NB_, 0,   t1_, tid);                                      \
    stage64(Bm, bcol, NB_, 64,  t1_, tid);                                      \
    stage64(Bm, bcol, NB_, 128, t1_, tid);                                      \
    stage64(Bm, bcol, NB_, 192, t1_, tid);                                      \
    RD_A(afB, CA_, 0, 1);                                                       \
    RD_B(CB_, 1);                                                               \
    MM(afA, 0, 0);                                                              \
    SB;                                                                         \
    /* p2: consume (afB,bq1); prefetch afA; stage A(t+2) full */                \
    stage64(Am, brow, SA_, 0,   t2_, tid);                                      \
    stage64(Am, brow, SA_, 64,  t2_, tid);                                      \
    stage64(Am, brow, SA_, 128, t2_, tid);                                      \
    stage64(Am, brow, SA_, 192, t2_, tid);                                      \
    RD_A(afA, CA_, 1, 0);                                                       \
    MM(afB, 1, 0);                                                              \
    SB;                                                                         \
    /* p3: consume (afA,bq0); prefetch afB; SINGLE sync point */                \
    RD_A(afB, CA_, 1, 1);                                                       \
    MM(afA, 0, 1);                                                              \
    VMW(4);                                                                     \
    LGKM0;                                                                      \
    BAR; SB;                                                                    \
    /* p4: consume (afB,bq1); prefetch (afA,bq0) from next-tile buffers */      \
    RD_A(afA, NA_, 0, 0);                                                       \
    RD_B(NB_, 0);                                                               \
    MM(afB, 1, 1);                                                              \
    SB;                                                                         \
} while (0)

__global__ __launch_bounds__(512, 2) void gemm256_kernel(
    const bf16_t* __restrict__ Am,   // [MTOT, IN_F]
    const bf16_t* __restrict__ Bm,   // [OUT_F, IN_F]
    float* __restrict__ C)           // [MTOT, OUT_F]
{
    __shared__ bf16_t a0[256 * 64], a1[256 * 64], a2[256 * 64];  // 96 KB
    __shared__ bf16_t b0[256 * 64], b1[256 * 64];                // 64 KB

    const int tid  = threadIdx.x;
    const int lane = tid & 63;
    const int lr   = lane & 15;
    const int hi   = lane >> 4;
    const int wave = tid >> 6;
    const int wm   = wave >> 2;      // 0..1
    const int wn   = wave & 3;       // 0..3

    // XCD-aware bijective swizzle (nwg = 1024, % 8 == 0)
    const int bid = blockIdx.x;
    const int swz = (bid & 7) * 128 + (bid >> 3);
    const size_t brow = (size_t)(swz >> 4) * 256;   // 64 row-blocks
    const size_t bcol = (size_t)(swz & 15) * 256;   // 16 col-blocks

    f32x4 acc[8][4];
#pragma unroll
    for (int i = 0; i < 8; ++i)
#pragma unroll
        for (int n = 0; n < 4; ++n)
#pragma unroll
            for (int q = 0; q < 4; ++q) acc[i][n][q] = 0.0f;

    bf16x8 bq[2][4];
    bf16x8 afA[4], afB[4];

    // Prologue: A(0)->a0, B(0)->b0, A(1)->a1 (12 loads); VMW(4) drains
    // A(0)+B(0), keeps A(1)x4 in flight -- matches steady p1 entry (queue=4).
    stage64(Am, brow, a0, 0,   0, tid);
    stage64(Am, brow, a0, 64,  0, tid);
    stage64(Am, brow, a0, 128, 0, tid);
    stage64(Am, brow, a0, 192, 0, tid);
    stage64(Bm, bcol, b0, 0,   0, tid);
    stage64(Bm, bcol, b0, 64,  0, tid);
    stage64(Bm, bcol, b0, 128, 0, tid);
    stage64(Bm, bcol, b0, 192, 0, tid);
    stage64(Am, brow, a1, 0,   1, tid);
    stage64(Am, brow, a1, 64,  1, tid);
    stage64(Am, brow, a1, 128, 1, tid);
    stage64(Am, brow, a1, 192, 1, tid);
    VMW(4);
    BAR; SB;
    // initial fragments for p1(0)'s MFMA (regions drained above, post-BAR)
    RD_A(afA, a0, 0, 0);
    RD_B(b0, 0);

    // rotation period lcm(3,2)=6; 64 tiles = 10*6 + 4 tail
    for (int tt = 0; tt < NT - 4; tt += 6) {
        TILE(tt + 0, a0, a1, a2, b0, b1);
        TILE(tt + 1, a1, a2, a0, b1, b0);
        TILE(tt + 2, a2, a0, a1, b0, b1);
        TILE(tt + 3, a0, a1, a2, b1, b0);
        TILE(tt + 4, a1, a2, a0, b0, b1);
        TILE(tt + 5, a2, a0, a1, b1, b0);
    }
    TILE(60, a0, a1, a2, b0, b1);
    TILE(61, a1, a2, a0, b1, b0);
    TILE(62, a2, a0, a1, b0, b1);
    TILE(63, a0, a1, a2, b1, b0);

    // Epilogue: D col = lane&15, row = (lane>>4)*4 + reg  [m89-verified]
    const size_t r0 = brow + (size_t)wm * 128 + hi * 4;
    const size_t c0 = bcol + (size_t)wn * 64 + lr;
#pragma unroll
    for (int mi = 0; mi < 8; ++mi)
#pragma unroll
        for (int n = 0; n < 4; ++n)
#pragma unroll
            for (int q = 0; q < 4; ++q)
                C[(r0 + mi * 16 + q) * OUT_F + c0 + n * 16] = acc[mi][n][q];
}

// ---------------------------------------------------------------------------
extern "C" void kernel_launch(void* const* d_in, const int* in_sizes, int n_in,
                              void* d_out, int out_size, void* d_ws, size_t ws_size,
                              hipStream_t stream)
{
    const float* x      = (const float*)d_in[0];
    const float* weight = (const float*)d_in[1];
    const float* loraP  = (const float*)d_in[2];
    const float* sigma  = (const float*)d_in[3];
    const float* loraQ  = (const float*)d_in[4];
    float* out = (float*)d_out;

    bf16_t* Wb = (bf16_t*)d_ws;                                      // 32 MiB
    bf16_t* Xb = (bf16_t*)((char*)d_ws + (size_t)OUT_F * IN_F * 2);  // 128 MiB

    prep_kernel<<<CVT_BLOCKS + FOLD_BLOCKS, 256, 0, stream>>>(
        x, Xb, weight, loraP, sigma, loraQ, Wb);

    gemm256_kernel<<<(MTOT / 256) * (OUT_F / 256), 512, 0, stream>>>(Xb, Wb, out);
}

// Round 16
// 599.292 us; speedup vs baseline: 1.0127x; 1.0127x over previous
//
#include <hip/hip_runtime.h>
#include <hip/hip_bf16.h>
#include <stdint.h>

typedef __bf16 bf16_t;
typedef __attribute__((ext_vector_type(8))) __bf16 bf16x8;
typedef __attribute__((ext_vector_type(4))) __bf16 bf16x4;
typedef __attribute__((ext_vector_type(4))) float f32x4;

constexpr int IN_F   = 4096;
constexpr int OUT_F  = 4096;
constexpr int RANKC  = 12;
constexpr float SCAL = 16.0f / 12.0f;
constexpr int MTOT   = 4 * 4096;   // B*S = 16384
constexpr int NT     = IN_F / 64;  // 64 K-tiles

// prep kernel grid split (one-shot blocks: verified best; grid-stride regressed)
constexpr int CVT_BLOCKS  = (MTOT * IN_F) / (256 * 8);     // 32768
constexpr int FOLD_BLOCKS = (OUT_F * IN_F) / (256 * 4);    // 16384

typedef __attribute__((address_space(1))) const unsigned int uint_g;
typedef __attribute__((address_space(3))) unsigned int uint_l;

__device__ __forceinline__ void gload_lds16(const void* g, void* l) {
    __builtin_amdgcn_global_load_lds((uint_g*)(uintptr_t)g,
                                     (uint_l*)(uintptr_t)l,
                                     16, 0, 0);
}

// ---------------------------------------------------------------------------
// Kernel 1 (merged prep):
//   blocks [0, CVT_BLOCKS):      x fp32 -> bf16 (8 elems/thread)
//   blocks [CVT_BLOCKS, +FOLD):  Wb = bf16(W + SCAL * (P*sigma) Q^T)  (4/thr)
// ---------------------------------------------------------------------------
__global__ __launch_bounds__(256) void prep_kernel(
    const float* __restrict__ X,  bf16_t* __restrict__ Xb,
    const float* __restrict__ W,  const float* __restrict__ P,
    const float* __restrict__ sg, const float* __restrict__ Q,
    bf16_t* __restrict__ Wb)
{
    if (blockIdx.x < CVT_BLOCKS) {
        const size_t base = ((size_t)blockIdx.x * 256 + threadIdx.x) * 8;
        const float4 a = *reinterpret_cast<const float4*>(X + base);
        const float4 b = *reinterpret_cast<const float4*>(X + base + 4);
        bf16x8 ob;
        ob[0] = (bf16_t)a.x; ob[1] = (bf16_t)a.y; ob[2] = (bf16_t)a.z; ob[3] = (bf16_t)a.w;
        ob[4] = (bf16_t)b.x; ob[5] = (bf16_t)b.y; ob[6] = (bf16_t)b.z; ob[7] = (bf16_t)b.w;
        *reinterpret_cast<bf16x8*>(Xb + base) = ob;
    } else {
        const int t    = (blockIdx.x - CVT_BLOCKS) * 256 + threadIdx.x;
        const int base = t * 4;
        const int o    = base >> 12;            // IN_F = 4096 = 2^12
        const int i0   = base & (IN_F - 1);

        float psig[RANKC];
#pragma unroll
        for (int r = 0; r < RANKC; ++r)
            psig[r] = P[o * RANKC + r] * sg[r] * SCAL;

        const float4 w = *reinterpret_cast<const float4*>(W + base);
        float out[4] = {w.x, w.y, w.z, w.w};
#pragma unroll
        for (int j = 0; j < 4; ++j) {
            const float* q = Q + (size_t)(i0 + j) * RANKC;
            float d = 0.0f;
#pragma unroll
            for (int r = 0; r < RANKC; ++r) d += psig[r] * q[r];
            out[j] += d;
        }
        bf16x4 ob;
#pragma unroll
        for (int j = 0; j < 4; ++j) ob[j] = (bf16_t)out[j];
        *reinterpret_cast<bf16x4*>(Wb + base) = ob;
    }
}

// ---------------------------------------------------------------------------
// Kernel 2: 256x256 4-phase pipelined GEMM -- R12 kernel VERBATIM (verified
// best: ~450 us, MfmaUtil 58, 0 conflicts; total 598.9/599.8 over two runs).
// Barriers only at p1-end (VMW(4)) and p3-end (VMW(2)).
// Session ledger: 4->2 barriers +4% (R12); 2->1 barrier neutral (R15);
// vmcnt slack 0 (R3); reg-prefetch +3% (R5); 32x32 shape -5% (R6); fused-A
// reg-staging -2x (R7); max-lead staging 0 (R9); 2 blocks/CU impossible
// (R10: acc=128 AGPR alone; halved budget spills 16x). This is the
// structure's ceiling (~58% MFMA), not a HW roofline.
//
// Publish safety (DMA->read):
//   p1-end VMW(4)+BAR drains A-H1(t)          [read p2/p3 heads]
//   p3-end VMW(2)+BAR drains A-H0(t+1)+B(t+1) [read p4/p1' heads]
//   queue 4->6->8->2->4, never 0.
// WAR safety: every region's overwrite is >=1 retained barrier after its
// last read's MFMA-consumption (traced per region; drift windows touch
// only disjoint buffers).
// ---------------------------------------------------------------------------
__device__ __forceinline__ void stage64(const bf16_t* __restrict__ g, size_t grow0,
                                        bf16_t* lt, int ldrow0, int kt, int tid)
{
    const int rr  = tid >> 3;                       // 0..63 within region
    const int c16 = (tid & 7) ^ (rr & 7);           // inverse-swizzled source chunk
    const bf16_t* src = g + (grow0 + (size_t)(ldrow0 + rr)) * IN_F + kt * 64 + c16 * 8;
    gload_lds16(src, lt + ldrow0 * 64 + tid * 8);   // linear LDS dest
}

#define VMW(N) asm volatile("s_waitcnt vmcnt(" #N ")" ::: "memory")
#define BAR    __builtin_amdgcn_s_barrier()
#define SB     __builtin_amdgcn_sched_barrier(0)

#define RD_A(DST, BUF, MH, KK) do {                                             \
    _Pragma("unroll")                                                           \
    for (int m_ = 0; m_ < 4; ++m_)                                              \
        DST[m_] = *(const bf16x8*)&BUF[(wm * 128 + (MH) * 64 + m_ * 16 + lr) * 64 \
                                       + (((KK) * 4 + hi) ^ (lr & 7)) * 8];     \
} while (0)

#define RD_B(BUF, KK) do {                                                      \
    _Pragma("unroll")                                                           \
    for (int n_ = 0; n_ < 4; ++n_)                                              \
        bq[KK][n_] = *(const bf16x8*)&BUF[(wn * 64 + n_ * 16 + lr) * 64         \
                                       + (((KK) * 4 + hi) ^ (lr & 7)) * 8];     \
} while (0)

#define MM(AF, KK, MH) do {                                                     \
    __builtin_amdgcn_s_setprio(1);                                              \
    _Pragma("unroll")                                                           \
    for (int m_ = 0; m_ < 4; ++m_)                                              \
        _Pragma("unroll")                                                       \
        for (int n_ = 0; n_ < 4; ++n_)                                          \
            acc[(MH) * 4 + m_][n_] = __builtin_amdgcn_mfma_f32_16x16x32_bf16(   \
                AF[m_], bq[KK][n_], acc[(MH) * 4 + m_][n_], 0, 0, 0);           \
    __builtin_amdgcn_s_setprio(0);                                              \
} while (0)

#define TILE(T, CA_, CB_, NA_, NB_) do {                                        \
    const int t1_ = ((T) + 1 < NT) ? (T) + 1 : NT - 1;                          \
    const int t2_ = ((T) + 2 < NT) ? (T) + 2 : NT - 1;                          \
    /* p1: consume (afA,bq0); prefetch (afB,bq1) for p2 */                      \
    stage64(Bm, bcol, NB_, 0,   t1_, tid);                                      \
    stage64(Bm, bcol, NB_, 64,  t1_, tid);                                      \
    RD_A(afB, CA_, 0, 1);                                                       \
    RD_B(CB_, 1);                                                               \
    MM(afA, 0, 0);                                                              \
    VMW(4);                                                                     \
    BAR; SB;                                                                    \
    /* p2: consume (afB,bq1); prefetch afA for p3  [no barrier at end] */       \
    stage64(Bm, bcol, NB_, 128, t1_, tid);                                      \
    stage64(Bm, bcol, NB_, 192, t1_, tid);                                      \
    RD_A(afA, CA_, 1, 0);                                                       \
    MM(afB, 1, 0);                                                              \
    SB;                                                                         \
    /* p3: consume (afA,bq0); prefetch afB for p4 */                            \
    stage64(Am, brow, NA_, 64,  t1_, tid);                                      \
    stage64(Am, brow, NA_, 192, t1_, tid);                                      \
    RD_A(afB, CA_, 1, 1);                                                       \
    MM(afA, 0, 1);                                                              \
    VMW(2);                                                                     \
    BAR; SB;                                                                    \
    /* p4: consume (afB,bq1); prefetch (afA,bq0) from next bufs                 \
       [no barrier at end] */                                                   \
    stage64(Am, brow, CA_, 0,   t2_, tid);                                      \
    stage64(Am, brow, CA_, 128, t2_, tid);                                      \
    RD_A(afA, NA_, 0, 0);                                                       \
    RD_B(NB_, 0);                                                               \
    MM(afB, 1, 1);                                                              \
    SB;                                                                         \
} while (0)

__global__ __launch_bounds__(512, 2) void gemm256_kernel(
    const bf16_t* __restrict__ Am,   // [MTOT, IN_F]
    const bf16_t* __restrict__ Bm,   // [OUT_F, IN_F]
    float* __restrict__ C)           // [MTOT, OUT_F]
{
    __shared__ bf16_t sA0[256 * 64], sB0[256 * 64], sA1[256 * 64], sB1[256 * 64];

    const int tid  = threadIdx.x;
    const int lane = tid & 63;
    const int lr   = lane & 15;
    const int hi   = lane >> 4;
    const int wave = tid >> 6;
    const int wm   = wave >> 2;      // 0..1
    const int wn   = wave & 3;       // 0..3

    // XCD-aware bijective swizzle (nwg = 1024, % 8 == 0)
    const int bid = blockIdx.x;
    const int swz = (bid & 7) * 128 + (bid >> 3);
    const size_t brow = (size_t)(swz >> 4) * 256;   // 64 row-blocks
    const size_t bcol = (size_t)(swz & 15) * 256;   // 16 col-blocks

    f32x4 acc[8][4];
#pragma unroll
    for (int i = 0; i < 8; ++i)
#pragma unroll
        for (int n = 0; n < 4; ++n)
#pragma unroll
            for (int q = 0; q < 4; ++q) acc[i][n][q] = 0.0f;

    bf16x8 bq[2][4];
    bf16x8 afA[4], afB[4];

    // Prologue: drain A-H0(0)+B(0) with VMW(4); leave [A-H1(0)2, A-H0(1)2]
    // in flight -- matches the steady-state p1 entry queue.
    stage64(Am, brow, sA0, 0,   0, tid);   // A-H0(0)
    stage64(Am, brow, sA0, 128, 0, tid);
    stage64(Bm, bcol, sB0, 0,   0, tid);   // B(0)
    stage64(Bm, bcol, sB0, 64,  0, tid);
    stage64(Bm, bcol, sB0, 128, 0, tid);
    stage64(Bm, bcol, sB0, 192, 0, tid);
    stage64(Am, brow, sA0, 64,  0, tid);   // A-H1(0)
    stage64(Am, brow, sA0, 192, 0, tid);
    stage64(Am, brow, sA1, 0,   1, tid);   // A-H0(1)
    stage64(Am, brow, sA1, 128, 1, tid);
    VMW(4);
    BAR; SB;
    // initial fragments for p1(0)'s MFMA (regions drained above, post-BAR)
    RD_A(afA, sA0, 0, 0);
    RD_B(sB0, 0);

    for (int tt = 0; tt < NT; tt += 2) {
        TILE(tt,     sA0, sB0, sA1, sB1);
        TILE(tt + 1, sA1, sB1, sA0, sB0);
    }

    // Epilogue: D col = lane&15, row = (lane>>4)*4 + reg  [m89-verified]
    const size_t r0 = brow + (size_t)wm * 128 + hi * 4;
    const size_t c0 = bcol + (size_t)wn * 64 + lr;
#pragma unroll
    for (int mi = 0; mi < 8; ++mi)
#pragma unroll
        for (int n = 0; n < 4; ++n)
#pragma unroll
            for (int q = 0; q < 4; ++q)
                C[(r0 + mi * 16 + q) * OUT_F + c0 + n * 16] = acc[mi][n][q];
}

// ---------------------------------------------------------------------------
extern "C" void kernel_launch(void* const* d_in, const int* in_sizes, int n_in,
                              void* d_out, int out_size, void* d_ws, size_t ws_size,
                              hipStream_t stream)
{
    const float* x      = (const float*)d_in[0];
    const float* weight = (const float*)d_in[1];
    const float* loraP  = (const float*)d_in[2];
    const float* sigma  = (const float*)d_in[3];
    const float* loraQ  = (const float*)d_in[4];
    float* out = (float*)d_out;

    bf16_t* Wb = (bf16_t*)d_ws;                                      // 32 MiB
    bf16_t* Xb = (bf16_t*)((char*)d_ws + (size_t)OUT_F * IN_F * 2);  // 128 MiB

    prep_kernel<<<CVT_BLOCKS + FOLD_BLOCKS, 256, 0, stream>>>(
        x, Xb, weight, loraP, sigma, loraQ, Wb);

    gemm256_kernel<<<(MTOT / 256) * (OUT_F / 256), 512, 0, stream>>>(Xb, Wb, out);
}